// Round 2
// baseline (76.248 us; speedup 1.0000x reference)
//
#include <hip/hip_runtime.h>
#include <hip/hip_bf16.h>
#include <math.h>

// Problem constants (fixed by setup_inputs in the reference):
//   features: [B=2, C=512, H=50, W=64] float32
//   roiss:    [B=2, N=128, 4]          float32  (x1,y1,x2,y2 pixel coords)
//   out:      [B, N, C]                float32
#define IMG_W_F 1024.0f
#define IMG_H_F 800.0f

// ---------------------------------------------------------------------------
// Kernel 1: tiled transpose  [B, C, HW] -> [B, HW, C]
// 32x32 tiles via LDS (padded stride 33 to kill bank conflicts).
// C=512 and HW=3200 are both multiples of 32 -> no edge handling needed.
// ---------------------------------------------------------------------------
__global__ __launch_bounds__(256) void transpose_chw_to_hwc(
    const float* __restrict__ in,   // [B, C, HW]
    float* __restrict__ out,        // [B, HW, C]
    int C, int HW)
{
    __shared__ float tile[32][33];
    const int b   = blockIdx.z;
    const int hw0 = blockIdx.x * 32;
    const int c0  = blockIdx.y * 32;
    const int tx  = threadIdx.x;    // 0..31
    const int ty  = threadIdx.y;    // 0..7

    const float* ib = in  + (size_t)b * C * HW;
    float*       ob = out + (size_t)b * C * HW;

#pragma unroll
    for (int i = 0; i < 4; ++i) {
        const int r = ty + i * 8;                       // c offset in tile
        tile[r][tx] = ib[(size_t)(c0 + r) * HW + (hw0 + tx)];  // coalesced in hw
    }
    __syncthreads();
#pragma unroll
    for (int i = 0; i < 4; ++i) {
        const int r = ty + i * 8;                       // hw offset in tile
        ob[(size_t)(hw0 + r) * C + (c0 + tx)] = tile[tx][r];   // coalesced in c
    }
}

// ---------------------------------------------------------------------------
// Kernel 2: ROI max-pool over channels-last features.
// One block (512 threads) per ROI; thread = channel -> every region-cell read
// is a fully coalesced 512-float contiguous span.
// ---------------------------------------------------------------------------
__global__ __launch_bounds__(512) void roipool_cl_kernel(
    const float* __restrict__ ft,     // [B, H*W, C]
    const float* __restrict__ rois,   // [B, N, 4]
    float* __restrict__ out,          // [B, N, C]
    int C, int H, int W, int N)
{
    const int bn = blockIdx.x;        // b * N + n
    const int b  = bn / N;

    const float* roi = rois + (size_t)bn * 4;
    const float rx1 = roi[0], ry1 = roi[1], rx2 = roi[2], ry2 = roi[3];

    // Replicate reference math exactly (same fp32 op order).
    int x1 = (int)floorf(rx1 / IMG_W_F * (float)W);
    int y1 = (int)floorf(ry1 / IMG_H_F * (float)H);
    int x2 = (int)ceilf (rx2 / IMG_W_F * (float)W);
    int y2 = (int)ceilf (ry2 / IMG_H_F * (float)H);
    x1 = max(x1, 0);
    y1 = max(y1, 0);
    x2 = max(x2, 0);
    y2 = max(y2, 0);
    if (x1 == 0 && x2 == 0) x2 = 1;     // degenerate-box fixes, reference order
    if (y1 == 0 && y2 == 0) y2 = 1;
    if (x1 >= W) x1 = W - 1;
    if (y1 >= H) y1 = H - 1;
    const int ye = min(y2, H);
    const int xe = min(x2, W);

    const float* fb = ft + (size_t)b * H * W * C;

    for (int c = threadIdx.x; c < C; c += blockDim.x) {
        float m = -INFINITY;
        for (int y = y1; y < ye; ++y) {
            const float* fr = fb + ((size_t)y * W) * C + c;
            for (int x = x1; x < xe; ++x) {
                m = fmaxf(m, fr[(size_t)x * C]);
            }
        }
        out[(size_t)bn * C + c] = m;
    }
}

// ---------------------------------------------------------------------------
// Fallback (R1-verified): direct pool over [B, C, H, W], used only if the
// workspace is too small for the transposed copy.
// ---------------------------------------------------------------------------
__global__ __launch_bounds__(256) void roipool_direct_kernel(
    const float* __restrict__ feat,   // [B, C, H, W]
    const float* __restrict__ rois,   // [B, N, 4]
    float* __restrict__ out,          // [B, N, C]
    int B, int C, int H, int W, int N)
{
    const int bn = blockIdx.x;
    const int b  = bn / N;

    const float* roi = rois + (size_t)bn * 4;
    const float rx1 = roi[0], ry1 = roi[1], rx2 = roi[2], ry2 = roi[3];

    int x1 = (int)floorf(rx1 / IMG_W_F * (float)W);
    int y1 = (int)floorf(ry1 / IMG_H_F * (float)H);
    int x2 = (int)ceilf (rx2 / IMG_W_F * (float)W);
    int y2 = (int)ceilf (ry2 / IMG_H_F * (float)H);
    x1 = max(x1, 0); y1 = max(y1, 0); x2 = max(x2, 0); y2 = max(y2, 0);
    if (x1 == 0 && x2 == 0) x2 = 1;
    if (y1 == 0 && y2 == 0) y2 = 1;
    if (x1 >= W) x1 = W - 1;
    if (y1 >= H) y1 = H - 1;
    const int ye = min(y2, H);
    const int xe = min(x2, W);

    const float* fb = feat + (size_t)b * C * H * W;
    float* ob = out + (size_t)bn * C;

    for (int c = threadIdx.x; c < C; c += blockDim.x) {
        const float* fc = fb + (size_t)c * H * W;
        float m = -INFINITY;
        for (int y = y1; y < ye; ++y) {
            const float* fr = fc + (size_t)y * W;
            for (int x = x1; x < xe; ++x) m = fmaxf(m, fr[x]);
        }
        ob[c] = m;
    }
}

extern "C" void kernel_launch(void* const* d_in, const int* in_sizes, int n_in,
                              void* d_out, int out_size, void* d_ws, size_t ws_size,
                              hipStream_t stream) {
    const int B = 2, C = 512, H = 50, W = 64, N = 128;
    const int HW = H * W;  // 3200

    const float* feat = (const float*)d_in[0];
    const float* rois = (const float*)d_in[1];
    float* out = (float*)d_out;

    const size_t need = (size_t)B * C * HW * sizeof(float);  // 13,107,200 B

    if (ws_size >= need) {
        float* feat_t = (float*)d_ws;   // [B, HW, C]

        dim3 tgrid(HW / 32, C / 32, B);   // 100 x 16 x 2
        dim3 tblock(32, 8);
        transpose_chw_to_hwc<<<tgrid, tblock, 0, stream>>>(feat, feat_t, C, HW);

        dim3 pgrid(B * N);                // one block per ROI
        dim3 pblock(512);                 // thread = channel
        roipool_cl_kernel<<<pgrid, pblock, 0, stream>>>(feat_t, rois, out, C, H, W, N);
    } else {
        dim3 grid(B * N);
        dim3 block(256);
        roipool_direct_kernel<<<grid, block, 0, stream>>>(feat, rois, out, B, C, H, W, N);
    }
}

// Round 3
// 75.188 us; speedup vs baseline: 1.0141x; 1.0141x over previous
//
#include <hip/hip_runtime.h>
#include <hip/hip_bf16.h>
#include <math.h>

// Problem constants (fixed by setup_inputs in the reference):
//   features: [B=2, C=512, H=50, W=64] float32
//   roiss:    [B=2, N=128, 4]          float32  (x1,y1,x2,y2 pixel coords)
//   out:      [B, N, C]                float32
#define IMG_W_F 1024.0f
#define IMG_H_F 800.0f

// ---------------------------------------------------------------------------
// Kernel 1: tiled transpose  [B, C, HW] -> [B, HW, C], float4 both directions.
// 64x64 tile via LDS (stride 65 -> at most 2-way bank aliasing, which is free
// on CDNA4). HW=3200 and C=512 are multiples of 64 -> no edge handling.
// LDS: 64*65*4 B = 16.6 KiB -> ~3 blocks/CU.
// ---------------------------------------------------------------------------
__global__ __launch_bounds__(256) void transpose_chw_to_hwc(
    const float* __restrict__ in,   // [B, C, HW]
    float* __restrict__ out,        // [B, HW, C]
    int C, int HW)
{
    __shared__ float tile[64][65];
    const int b   = blockIdx.z;
    const int hw0 = blockIdx.x * 64;
    const int c0  = blockIdx.y * 64;
    const int t   = threadIdx.x;          // 0..255
    const int sub = t & 15;               // 0..15  -> float4 column group
    const int row = t >> 4;               // 0..15  -> row within pass

    const float* ib = in  + (size_t)b * C * HW;
    float*       ob = out + (size_t)b * C * HW;

    // Phase 1: read rows along hw (coalesced float4), scatter into tile.
#pragma unroll
    for (int it = 0; it < 4; ++it) {
        const int cr = it * 16 + row;                       // 0..63
        const float4 v = *(const float4*)&ib[(size_t)(c0 + cr) * HW + (hw0 + sub * 4)];
        tile[cr][sub * 4 + 0] = v.x;
        tile[cr][sub * 4 + 1] = v.y;
        tile[cr][sub * 4 + 2] = v.z;
        tile[cr][sub * 4 + 3] = v.w;
    }
    __syncthreads();

    // Phase 2: gather transposed, write rows along c (coalesced float4).
#pragma unroll
    for (int it = 0; it < 4; ++it) {
        const int hr = it * 16 + row;                       // 0..63
        float4 w;
        w.x = tile[sub * 4 + 0][hr];
        w.y = tile[sub * 4 + 1][hr];
        w.z = tile[sub * 4 + 2][hr];
        w.w = tile[sub * 4 + 3][hr];
        *(float4*)&ob[(size_t)(hw0 + hr) * C + (c0 + sub * 4)] = w;
    }
}

// ---------------------------------------------------------------------------
// Kernel 2: ROI max-pool over channels-last features, float2 per thread.
// One block (256 threads) per ROI; thread t owns channels {2t, 2t+1} -> each
// region-cell read is a fully coalesced contiguous 2 KB span per block.
// ---------------------------------------------------------------------------
__global__ __launch_bounds__(256) void roipool_cl_kernel(
    const float* __restrict__ ft,     // [B, H*W, C]
    const float* __restrict__ rois,   // [B, N, 4]
    float* __restrict__ out,          // [B, N, C]
    int C, int H, int W, int N)
{
    const int bn = blockIdx.x;        // b * N + n
    const int b  = bn / N;

    const float* roi = rois + (size_t)bn * 4;
    const float rx1 = roi[0], ry1 = roi[1], rx2 = roi[2], ry2 = roi[3];

    // Replicate reference math exactly (same fp32 op order).
    int x1 = (int)floorf(rx1 / IMG_W_F * (float)W);
    int y1 = (int)floorf(ry1 / IMG_H_F * (float)H);
    int x2 = (int)ceilf (rx2 / IMG_W_F * (float)W);
    int y2 = (int)ceilf (ry2 / IMG_H_F * (float)H);
    x1 = max(x1, 0);
    y1 = max(y1, 0);
    x2 = max(x2, 0);
    y2 = max(y2, 0);
    if (x1 == 0 && x2 == 0) x2 = 1;     // degenerate-box fixes, reference order
    if (y1 == 0 && y2 == 0) y2 = 1;
    if (x1 >= W) x1 = W - 1;
    if (y1 >= H) y1 = H - 1;
    const int ye = min(y2, H);
    const int xe = min(x2, W);

    const float2* fb2 = (const float2*)(ft + (size_t)b * H * W * C);
    const int c2 = threadIdx.x;         // 0..255 -> channels 2*c2, 2*c2+1
    const int C2 = C >> 1;              // 256 float2 per spatial cell

    float2 m = make_float2(-INFINITY, -INFINITY);
    for (int y = y1; y < ye; ++y) {
        const float2* fr = fb2 + (size_t)(y * W) * C2 + c2;
        for (int x = x1; x < xe; ++x) {
            const float2 v = fr[(size_t)x * C2];
            m.x = fmaxf(m.x, v.x);
            m.y = fmaxf(m.y, v.y);
        }
    }
    ((float2*)out)[(size_t)bn * C2 + c2] = m;
}

// ---------------------------------------------------------------------------
// Fallback (R1-verified): direct pool over [B, C, H, W], used only if the
// workspace is too small for the transposed copy.
// ---------------------------------------------------------------------------
__global__ __launch_bounds__(256) void roipool_direct_kernel(
    const float* __restrict__ feat,   // [B, C, H, W]
    const float* __restrict__ rois,   // [B, N, 4]
    float* __restrict__ out,          // [B, N, C]
    int B, int C, int H, int W, int N)
{
    const int bn = blockIdx.x;
    const int b  = bn / N;

    const float* roi = rois + (size_t)bn * 4;
    const float rx1 = roi[0], ry1 = roi[1], rx2 = roi[2], ry2 = roi[3];

    int x1 = (int)floorf(rx1 / IMG_W_F * (float)W);
    int y1 = (int)floorf(ry1 / IMG_H_F * (float)H);
    int x2 = (int)ceilf (rx2 / IMG_W_F * (float)W);
    int y2 = (int)ceilf (ry2 / IMG_H_F * (float)H);
    x1 = max(x1, 0); y1 = max(y1, 0); x2 = max(x2, 0); y2 = max(y2, 0);
    if (x1 == 0 && x2 == 0) x2 = 1;
    if (y1 == 0 && y2 == 0) y2 = 1;
    if (x1 >= W) x1 = W - 1;
    if (y1 >= H) y1 = H - 1;
    const int ye = min(y2, H);
    const int xe = min(x2, W);

    const float* fb = feat + (size_t)b * C * H * W;
    float* ob = out + (size_t)bn * C;

    for (int c = threadIdx.x; c < C; c += blockDim.x) {
        const float* fc = fb + (size_t)c * H * W;
        float m = -INFINITY;
        for (int y = y1; y < ye; ++y) {
            const float* fr = fc + (size_t)y * W;
            for (int x = x1; x < xe; ++x) m = fmaxf(m, fr[x]);
        }
        ob[c] = m;
    }
}

extern "C" void kernel_launch(void* const* d_in, const int* in_sizes, int n_in,
                              void* d_out, int out_size, void* d_ws, size_t ws_size,
                              hipStream_t stream) {
    const int B = 2, C = 512, H = 50, W = 64, N = 128;
    const int HW = H * W;  // 3200

    const float* feat = (const float*)d_in[0];
    const float* rois = (const float*)d_in[1];
    float* out = (float*)d_out;

    const size_t need = (size_t)B * C * HW * sizeof(float);  // 13,107,200 B

    if (ws_size >= need) {
        float* feat_t = (float*)d_ws;   // [B, HW, C]

        dim3 tgrid(HW / 64, C / 64, B);   // 50 x 8 x 2 = 800 blocks
        dim3 tblock(256);
        transpose_chw_to_hwc<<<tgrid, tblock, 0, stream>>>(feat, feat_t, C, HW);

        dim3 pgrid(B * N);                // one block per ROI
        dim3 pblock(256);                 // thread = float2 of channels
        roipool_cl_kernel<<<pgrid, pblock, 0, stream>>>(feat_t, rois, out, C, H, W, N);
    } else {
        dim3 grid(B * N);
        dim3 block(256);
        roipool_direct_kernel<<<grid, block, 0, stream>>>(feat, rois, out, B, C, H, W, N);
    }
}